// Round 1
// baseline (2122.436 us; speedup 1.0000x reference)
//
#include <hip/hip_runtime.h>
#include <hip/hip_bf16.h>
#include <math.h>

#define Bsz 8
#define Tsz 2048
#define Dsz 1024
#define HSsz 64

// ---------------------------------------------------------------------------
// Kernel 1: fused QKV projection.  out[row][c] = sum_d x[row][d]*W[c][d] + b[c]
// grid 256 blocks x 256 threads. Block covers 64 rows of B*T=16384.
// Thread: one output column c (tid&63), 16 rows (wave id = tid>>6), all 3 proj.
// x values are wave-uniform (same row for all 64 lanes) -> scalar-load friendly.
// W chunk staged in LDS [3][64][65]; reads are 2-way bank aliased (free).
// ---------------------------------------------------------------------------
__global__ __launch_bounds__(256) void qkv_kernel(
    const float* __restrict__ x,
    const float* __restrict__ Wq, const float* __restrict__ bq,
    const float* __restrict__ Wk, const float* __restrict__ bk,
    const float* __restrict__ Wv, const float* __restrict__ bv,
    float* __restrict__ qo, float* __restrict__ ko, float* __restrict__ vo)
{
    __shared__ float ws[3][64][65];
    const int tid = threadIdx.x;
    const int c   = tid & 63;
    const int rg  = __builtin_amdgcn_readfirstlane(tid >> 6);  // wave id 0..3
    const long r0 = (long)blockIdx.x * 64;

    float acc0[16], acc1[16], acc2[16];
#pragma unroll
    for (int r = 0; r < 16; ++r) { acc0[r] = 0.f; acc1[r] = 0.f; acc2[r] = 0.f; }

    for (int kk0 = 0; kk0 < Dsz; kk0 += 64) {
        __syncthreads();
        {
            const float* Wp[3] = {Wq, Wk, Wv};
#pragma unroll
            for (int s = 0; s < 12; ++s) {           // 3*64*16 = 3072 float4s
                const int f   = tid + s * 256;
                const int p   = f >> 10;             // constant per s after unroll
                const int rem = f & 1023;
                const int cc  = rem >> 4;
                const int k4  = rem & 15;
                const float4 w4 = *(const float4*)(Wp[p] + (size_t)cc * Dsz + kk0 + k4 * 4);
                ws[p][cc][k4 * 4 + 0] = w4.x;
                ws[p][cc][k4 * 4 + 1] = w4.y;
                ws[p][cc][k4 * 4 + 2] = w4.z;
                ws[p][cc][k4 * 4 + 3] = w4.w;
            }
        }
        __syncthreads();

        for (int k4 = 0; k4 < 16; ++k4) {
            float4 xr[16];
#pragma unroll
            for (int rr = 0; rr < 16; ++rr)
                xr[rr] = *(const float4*)(x + (size_t)(r0 + rg * 16 + rr) * Dsz + kk0 + k4 * 4);
#pragma unroll
            for (int kkk = 0; kkk < 4; ++kkk) {
                const float w0 = ws[0][c][k4 * 4 + kkk];
                const float w1 = ws[1][c][k4 * 4 + kkk];
                const float w2 = ws[2][c][k4 * 4 + kkk];
#pragma unroll
                for (int rr = 0; rr < 16; ++rr) {
                    const float xv = (kkk == 0) ? xr[rr].x :
                                     (kkk == 1) ? xr[rr].y :
                                     (kkk == 2) ? xr[rr].z : xr[rr].w;
                    acc0[rr] = fmaf(xv, w0, acc0[rr]);
                    acc1[rr] = fmaf(xv, w1, acc1[rr]);
                    acc2[rr] = fmaf(xv, w2, acc2[rr]);
                }
            }
        }
    }

    const float bqc = bq[c], bkc = bk[c], bvc = bv[c];
#pragma unroll
    for (int rr = 0; rr < 16; ++rr) {
        const size_t row = (size_t)(r0 + rg * 16 + rr);
        qo[row * HSsz + c] = acc0[rr] + bqc;
        ko[row * HSsz + c] = acc1[rr] + bkc;
        vo[row * HSsz + c] = acc2[rr] + bvc;
    }
}

// ---------------------------------------------------------------------------
// Kernel 2: fused flash-style attention with relative-position bias.
// grid 256 blocks x 256 threads. Block = 8 query positions (t0..t0+7) x all
// 8 batches, so rel_pos is streamed from HBM exactly once in total.
// Thread: row = (b,i) = tid>>2 (64 rows), channel quarter cp = tid&3; owns
// interleaved channels c = u*16 + cp*4 + w (u<4, w<4). q row chunk and the O
// accumulator live in registers. Per 16-key tile: partial scores over the
// 16-channel chunk, 2x shfl_xor to combine -> every thread holds the full 16
// scores of its row -> softmax bookkeeping fully in registers (no extra sync).
// LDS: k_s/v_s [8][16][68] (j-stride padded for write spread; reads 2-way),
//      r_s i-stride 1092 + c-swizzle (+8i) so reads are ~2-way (free).
// ---------------------------------------------------------------------------
__global__ __launch_bounds__(256) void attn_kernel(
    const float* __restrict__ qg, const float* __restrict__ kg,
    const float* __restrict__ vg, const float* __restrict__ rel,
    float* __restrict__ out)
{
    __shared__ float k_s[8][16][68];
    __shared__ float v_s[8][16][68];
    __shared__ float r_s[8 * 1092];

    const int tid = threadIdx.x;
    const int row = tid >> 2;      // 0..63
    const int b   = row >> 3;      // batch
    const int i   = row & 7;       // query offset within tile
    const int cp  = tid & 3;       // channel quarter
    const int t0  = blockIdx.x * 8;

    float qr[16];
    {
        const float* qp = qg + (size_t)(b * Tsz + t0 + i) * HSsz;
#pragma unroll
        for (int u = 0; u < 4; ++u) {
            const float4 t = *(const float4*)(qp + u * 16 + cp * 4);
            qr[u * 4 + 0] = t.x; qr[u * 4 + 1] = t.y;
            qr[u * 4 + 2] = t.z; qr[u * 4 + 3] = t.w;
        }
    }

    float O[16];
#pragma unroll
    for (int u = 0; u < 16; ++u) O[u] = 0.f;
    float m = -INFINITY, l = 0.f;

    for (int v0 = 0; v0 < Tsz; v0 += 16) {
        // ---- stage k, v, rel tiles (96 KB): 8 float4 of each per thread ----
#pragma unroll
        for (int s = 0; s < 8; ++s) {
            const int f  = tid + s * 256;     // 0..2047
            const int g  = f >> 8;            // b for k/v, i for rel
            const int jj = (f >> 4) & 15;
            const int c4 = f & 15;
            const float4 kk4 = *(const float4*)(kg + (size_t)(g * Tsz + v0 + jj) * HSsz + c4 * 4);
            const float4 vv4 = *(const float4*)(vg + (size_t)(g * Tsz + v0 + jj) * HSsz + c4 * 4);
            const float4 rr4 = *(const float4*)(rel + ((size_t)(t0 + g) * Tsz + (v0 + jj)) * HSsz + c4 * 4);
            *(float4*)(&k_s[g][jj][c4 * 4]) = kk4;
            *(float4*)(&v_s[g][jj][c4 * 4]) = vv4;
            *(float4*)(&r_s[g * 1092 + jj * 68 + ((c4 * 4 + 8 * g) & 63)]) = rr4;
        }
        __syncthreads();

        // ---- scores: S = 8*(q.k) + q.rel, partial over 16 channels ----
        float p[16];
#pragma unroll
        for (int j = 0; j < 16; ++j) {
            float a1 = 0.f, a2 = 0.f;
#pragma unroll
            for (int u = 0; u < 4; ++u) {
                const float4 kv = *(const float4*)(&k_s[b][j][u * 16 + cp * 4]);
                const float4 rv = *(const float4*)(&r_s[i * 1092 + j * 68 + ((u * 16 + cp * 4 + 8 * i) & 63)]);
                a1 = fmaf(qr[u * 4 + 0], kv.x, a1);
                a1 = fmaf(qr[u * 4 + 1], kv.y, a1);
                a1 = fmaf(qr[u * 4 + 2], kv.z, a1);
                a1 = fmaf(qr[u * 4 + 3], kv.w, a1);
                a2 = fmaf(qr[u * 4 + 0], rv.x, a2);
                a2 = fmaf(qr[u * 4 + 1], rv.y, a2);
                a2 = fmaf(qr[u * 4 + 2], rv.z, a2);
                a2 = fmaf(qr[u * 4 + 3], rv.w, a2);
            }
            float sc = 8.f * a1 + a2;
            sc += __shfl_xor(sc, 1);   // combine the 4 channel-quarters
            sc += __shfl_xor(sc, 2);   // all 4 threads get identical full score
            p[j] = sc;
        }

        // ---- online softmax, redundantly identical across the 4 row-threads ----
        float tmax = p[0];
#pragma unroll
        for (int j = 1; j < 16; ++j) tmax = fmaxf(tmax, p[j]);
        const float nm    = fmaxf(m, tmax);
        const float alpha = __expf(m - nm);        // first iter: exp(-inf) = 0
        float sum = 0.f;
#pragma unroll
        for (int j = 0; j < 16; ++j) { p[j] = __expf(p[j] - nm); sum += p[j]; }
        l = l * alpha + sum;
        m = nm;
#pragma unroll
        for (int u = 0; u < 16; ++u) O[u] *= alpha;

        // ---- O += p . v ----
#pragma unroll
        for (int j = 0; j < 16; ++j) {
            const float pj = p[j];
#pragma unroll
            for (int u = 0; u < 4; ++u) {
                const float4 vv = *(const float4*)(&v_s[b][j][u * 16 + cp * 4]);
                O[u * 4 + 0] = fmaf(pj, vv.x, O[u * 4 + 0]);
                O[u * 4 + 1] = fmaf(pj, vv.y, O[u * 4 + 1]);
                O[u * 4 + 2] = fmaf(pj, vv.z, O[u * 4 + 2]);
                O[u * 4 + 3] = fmaf(pj, vv.w, O[u * 4 + 3]);
            }
        }
        __syncthreads();   // protect next tile's staging
    }

    const float inv = 1.f / l;
    float* op = out + (size_t)(b * Tsz + t0 + i) * HSsz;
#pragma unroll
    for (int u = 0; u < 4; ++u) {
        float4 t;
        t.x = O[u * 4 + 0] * inv; t.y = O[u * 4 + 1] * inv;
        t.z = O[u * 4 + 2] * inv; t.w = O[u * 4 + 3] * inv;
        *(float4*)(op + u * 16 + cp * 4) = t;
    }
}

extern "C" void kernel_launch(void* const* d_in, const int* in_sizes, int n_in,
                              void* d_out, int out_size, void* d_ws, size_t ws_size,
                              hipStream_t stream)
{
    // setup_inputs order: x, Wk, bk, Wq, bq, Wv, bv, rel_pos
    const float* x   = (const float*)d_in[0];
    const float* Wk  = (const float*)d_in[1];
    const float* bk  = (const float*)d_in[2];
    const float* Wq  = (const float*)d_in[3];
    const float* bq  = (const float*)d_in[4];
    const float* Wv  = (const float*)d_in[5];
    const float* bv  = (const float*)d_in[6];
    const float* rel = (const float*)d_in[7];
    float* outp = (float*)d_out;

    const size_t n = (size_t)Bsz * Tsz * HSsz;   // 1,048,576 per tensor
    float* qo = (float*)d_ws;
    float* ko = qo + n;
    float* vo = ko + n;                           // ws usage: 12.6 MB

    qkv_kernel<<<256, 256, 0, stream>>>(x, Wq, bq, Wk, bk, Wv, bv, qo, ko, vo);
    attn_kernel<<<256, 256, 0, stream>>>(qo, ko, vo, rel, outp);
}